// Round 3
// baseline (139.318 us; speedup 1.0000x reference)
//
#include <hip/hip_runtime.h>

// CRF forward (log-partition), SEQ=512, BATCH=1024, TAGS=32, fp32 in/out.
//
// R12: ILP-2 per wave. Evidence from R9 (2 blk/CU, 57us) vs R11 (4 blk/CU,
// 61us): doubling resident waves left VALUBusy at ~53% -> NOT occupancy
// bound; the serial per-step chain (MFMA -> D*F -> pack -> MFMA) is. Fix:
// each wave now runs TWO independent 32-step chains (its 64 rows split in
// half, NC=16 chunks total). Chain Y's VALU work fills chain X's MFMA
// latency shadow (and vice versa) inside one in-order wave. The common
// all-ones-mask case executes both chains in ONE branch-free region so the
// compiler can interleave; rare masked steps take guarded fallbacks.
// Epilogue: 8 rounds, each wave does w*PY then (via 8-shfl redistribute)
// w*PX. VGPR ~110 -> 2 blocks/CU (intentional; occupancy proven non-binding).

constexpr int SEQ = 512, BATCH = 1024, TAGS = 32;
constexpr int NW = 8;        // waves per block
constexpr int LH = 32;       // steps per chain (2 chains/wave)
constexpr int RROW = 16;     // packed row stride in dwords (bf16 pairs)

#define LOG2E 1.4426950408889634f
#define LN2   0.6931471805599453f

typedef __attribute__((ext_vector_type(8))) short short8;
typedef __attribute__((ext_vector_type(4))) float float4v;
typedef __attribute__((ext_vector_type(4))) unsigned uint4v;
union Frag8 { unsigned u[4]; short8 v; };

__device__ __forceinline__ unsigned pk_rn(float x, float y) {  // bf16 pack, x->low
  return __builtin_amdgcn_perm(__float_as_uint(y) + 0x8000u,
                               __float_as_uint(x) + 0x8000u, 0x07060302u);
}
__device__ __forceinline__ unsigned pk_tr(float x, float y) {  // trunc pack, x->low
  return __builtin_amdgcn_perm(__float_as_uint(y), __float_as_uint(x), 0x07060302u);
}

extern "C" __global__ void __launch_bounds__(512, 4) crf_fused(
    const float* __restrict__ feats, const float* __restrict__ mask,
    const float* __restrict__ trans, float* __restrict__ out) {
  // per-wave staging: 66 rows (64 + prefetch over-read pad) x 16 dwords,
  // dword i of row t = pk_bf16(exp f_t(i), exp f_t(16+i)).
  __shared__ unsigned gst[NW][66 * RROW];  // 33,792 B
  __shared__ float c2s[NW];
  __shared__ __align__(16) float ws[TAGS];  // chain vector
  __shared__ float c2x;                     // chain renorm exponent accum

  const int wid = __builtin_amdgcn_readfirstlane((int)(threadIdx.x >> 6));
  const int lane = threadIdx.x & 63;
  const int b = blockIdx.x;  // one batch per block
  const int s = lane & 15, q = lane >> 4;
  unsigned* Wp = &gst[wid][0];

  // ---- stage: lane t handles row t (global row 64*wid+t) + its mask bit ----
  unsigned long long mb;
  {
    const float* fro = feats + ((size_t)(wid * 64 + lane) * BATCH + b) * TAGS;
    float4v fv[8];
#pragma unroll
    for (int i = 0; i < 8; ++i) fv[i] = *(const float4v*)(fro + 4 * i);
    const float mv = mask[(size_t)(wid * 64 + lane) * BATCH + b];
    mb = __ballot(mv != 0.0f);  // bit t = step t's mask
    unsigned* rp = Wp + lane * RROW;
#pragma unroll
    for (int g = 0; g < 4; ++g) {
      uint4v t;
#pragma unroll
      for (int k2 = 0; k2 < 4; ++k2) {
        const int j = 4 * g + k2;
        const float lo = __builtin_amdgcn_exp2f(fv[j >> 2][j & 3] * LOG2E);
        const float hi = __builtin_amdgcn_exp2f(fv[4 + (j >> 2)][j & 3] * LOG2E);
        t[k2] = pk_rn(lo, hi);  // low16 = f(j), high16 = f(16+j)
      }
      *(uint4v*)(rp + 4 * g) = t;
    }
  }

  // ---- constants: sigma-permuted E fragments (shared by both chains) ----
  int sig[8];
#pragma unroll
  for (int i = 0; i < 8; ++i) sig[i] = (i < 4) ? (4 * q + i) : (16 + 4 * q + (i - 4));
  Frag8 e0, e1;
#pragma unroll
  for (int p = 0; p < 4; ++p) {
    e0.u[p] = pk_rn(__builtin_amdgcn_exp2f(trans[s * TAGS + sig[2 * p]] * LOG2E),
                    __builtin_amdgcn_exp2f(trans[s * TAGS + sig[2 * p + 1]] * LOG2E));
    e1.u[p] = pk_rn(__builtin_amdgcn_exp2f(trans[(16 + s) * TAGS + sig[2 * p]] * LOG2E),
                    __builtin_amdgcn_exp2f(trans[(16 + s) * TAGS + sig[2 * p + 1]] * LOG2E));
  }

  // P (f32, D-layout): P_hc[p] = P[h*16+4q+p, c*16+s]. Init identity (both).
  float4v PX00 = {0,0,0,0}, PX01 = {0,0,0,0}, PX10 = {0,0,0,0}, PX11 = {0,0,0,0};
  float4v PY00 = {0,0,0,0}, PY01 = {0,0,0,0}, PY10 = {0,0,0,0}, PY11 = {0,0,0,0};
#pragma unroll
  for (int p = 0; p < 4; ++p) {
    float one = (4 * q + p == s) ? 1.f : 0.f;
    PX00[p] = one; PX11[p] = one; PY00[p] = one; PY11[p] = one;
  }
  Frag8 BX0, BX1, BY0, BY1;
  float c2X = 0.f, c2Y = 0.f;
  const float4v zerov = {0.f, 0.f, 0.f, 0.f};

#define PACK_B(B0, B1, P00, P01, P10, P11)                              \
  { B0.u[0] = pk_tr(P00[0], P00[1]); B0.u[1] = pk_tr(P00[2], P00[3]);   \
    B0.u[2] = pk_tr(P10[0], P10[1]); B0.u[3] = pk_tr(P10[2], P10[3]);   \
    B1.u[0] = pk_tr(P01[0], P01[1]); B1.u[1] = pk_tr(P01[2], P01[3]);   \
    B1.u[2] = pk_tr(P11[0], P11[1]); B1.u[3] = pk_tr(P11[2], P11[3]); }

  PACK_B(BX0, BX1, PX00, PX01, PX10, PX11)
  PACK_B(BY0, BY1, PY00, PY01, PY10, PY11)

  // one step of one chain: D = E*B (4 MFMA), P = D scaled rows by F, repack
#define STEP(U, B0, B1, P00, P01, P10, P11)                             \
  { float4v F0, F1;                                                     \
    _Pragma("unroll")                                                   \
    for (int i = 0; i < 4; ++i) {                                       \
      F0[i] = __uint_as_float(U[i] << 16);                              \
      F1[i] = __uint_as_float(U[i] & 0xffff0000u);                      \
    }                                                                   \
    float4v D00 = __builtin_amdgcn_mfma_f32_16x16x32_bf16(e0.v, B0.v, zerov, 0, 0, 0); \
    float4v D01 = __builtin_amdgcn_mfma_f32_16x16x32_bf16(e0.v, B1.v, zerov, 0, 0, 0); \
    float4v D10 = __builtin_amdgcn_mfma_f32_16x16x32_bf16(e1.v, B0.v, zerov, 0, 0, 0); \
    float4v D11 = __builtin_amdgcn_mfma_f32_16x16x32_bf16(e1.v, B1.v, zerov, 0, 0, 0); \
    P00 = D00 * F0; P01 = D01 * F0;                                     \
    P10 = D10 * F1; P11 = D11 * F1;                                     \
    PACK_B(B0, B1, P00, P01, P10, P11) }

#define RENORM(P00, P01, P10, P11, B0, B1, C2)                          \
  { float4v m4 = __builtin_elementwise_max(__builtin_elementwise_max(P00, P01), \
                                           __builtin_elementwise_max(P10, P11)); \
    float mx = fmaxf(fmaxf(m4[0], m4[1]), fmaxf(m4[2], m4[3]));         \
    mx = fmaxf(mx, __shfl_xor(mx, 1, 64));                              \
    mx = fmaxf(mx, __shfl_xor(mx, 2, 64));                              \
    mx = fmaxf(mx, __shfl_xor(mx, 4, 64));                              \
    mx = fmaxf(mx, __shfl_xor(mx, 8, 64));                              \
    mx = fmaxf(mx, __shfl_xor(mx, 16, 64));                             \
    mx = fmaxf(mx, __shfl_xor(mx, 32, 64));                             \
    int ex = (int)((__float_as_uint(mx) >> 23) & 0xFFu) - 127;          \
    float scl = __uint_as_float((unsigned)(127 - ex) << 23);            \
    P00 *= scl; P01 *= scl; P10 *= scl; P11 *= scl;                     \
    C2 += (float)ex;                                                    \
    PACK_B(B0, B1, P00, P01, P10, P11) }

  // read row t: one ds_read_b128; 16-lane broadcast, conflict-free
#define RDU(t) (*(const uint4v*)(Wp + (t) * RROW + 4 * q))

  uint4v UX = RDU(0), UY = RDU(32);

#pragma unroll 8
  for (int r = 0; r < LH; ++r) {
    // prefetch next rows (over-reads at r=31 hit row 32 (dead) / row 64 (pad))
    uint4v UXn = RDU(r + 1), UYn = RDU(33 + r);
    const bool bx = (mb >> r) & 1ull;
    const bool by = (mb >> (32 + r)) & 1ull;
    if (bx & by) {  // common case: both chains in one branch-free region
      STEP(UX, BX0, BX1, PX00, PX01, PX10, PX11)
      STEP(UY, BY0, BY1, PY00, PY01, PY10, PY11)
    } else {
      if (bx) STEP(UX, BX0, BX1, PX00, PX01, PX10, PX11)
      if (by) STEP(UY, BY0, BY1, PY00, PY01, PY10, PY11)
    }
    if ((r & 7) == 7) {  // renorm every 8 (growth <= 2^13.7/step)
      RENORM(PX00, PX01, PX10, PX11, BX0, BX1, c2X)
      RENORM(PY00, PY01, PY10, PY11, BY0, BY1, c2Y)
    }
    UX = UXn; UY = UYn;
  }

  // ---- epilogue: sequential chain w <- w*P_k over 16 chunks, 8 rounds ----
  // out = LN2 * (sum c2 + chain exps + log2( (E_end^T * P15 * ... * P0)[30] ))
  if (lane == 0) c2s[wid] = c2X + c2Y;
  if (threadIdx.x == 0) c2x = 0.f;
  __syncthreads();

  for (int k = NW - 1; k >= 0; --k) {
    if (wid == k) {
      float4v w0, w1;  // w[4q+p], w[16+4q+p]
      if (k == NW - 1) {
#pragma unroll
        for (int p = 0; p < 4; ++p) {
          w0[p] = __builtin_amdgcn_exp2f(trans[31 * TAGS + 4 * q + p] * LOG2E);
          w1[p] = __builtin_amdgcn_exp2f(trans[31 * TAGS + 16 + 4 * q + p] * LOG2E);
        }
      } else {
        w0 = *(const float4v*)(ws + 4 * q);
        w1 = *(const float4v*)(ws + 16 + 4 * q);
      }
      // hop 1: w <- w * PY (later chunk 2k+1)
      float ps = 0.f, pt = 0.f;
#pragma unroll
      for (int p = 0; p < 4; ++p) {
        ps += w0[p] * PY00[p] + w1[p] * PY10[p];
        pt += w0[p] * PY01[p] + w1[p] * PY11[p];
      }
      ps += __shfl_xor(ps, 16, 64); ps += __shfl_xor(ps, 32, 64);
      pt += __shfl_xor(pt, 16, 64); pt += __shfl_xor(pt, 32, 64);
      // redistribute: (ps,pt indexed by s) -> (w0,w1 indexed by 4q+p)
#pragma unroll
      for (int p = 0; p < 4; ++p) {
        w0[p] = __shfl(ps, 4 * q + p, 64);
        w1[p] = __shfl(pt, 4 * q + p, 64);
      }
      // hop 2: w <- w * PX (earlier chunk 2k)
      ps = 0.f; pt = 0.f;
#pragma unroll
      for (int p = 0; p < 4; ++p) {
        ps += w0[p] * PX00[p] + w1[p] * PX10[p];
        pt += w0[p] * PX01[p] + w1[p] * PX11[p];
      }
      ps += __shfl_xor(ps, 16, 64); ps += __shfl_xor(ps, 32, 64);
      pt += __shfl_xor(pt, 16, 64); pt += __shfl_xor(pt, 32, 64);
      if (k > 0) {
        // renorm w to keep the chain in fp32 range
        float mx = fmaxf(ps, pt);
        mx = fmaxf(mx, __shfl_xor(mx, 1, 64));
        mx = fmaxf(mx, __shfl_xor(mx, 2, 64));
        mx = fmaxf(mx, __shfl_xor(mx, 4, 64));
        mx = fmaxf(mx, __shfl_xor(mx, 8, 64));
        int ex = (int)((__float_as_uint(mx) >> 23) & 0xFFu) - 127;
        float scl = __uint_as_float((unsigned)(127 - ex) << 23);
        ps *= scl; pt *= scl;
        if (lane == 0) c2x += (float)ex;
        if (lane < 16) { ws[lane] = ps; ws[16 + lane] = pt; }
      } else if (lane == 14) {
        // element 30 = col 16+s with s==14 -> pt on lane 14
        float c2t = ((c2s[0] + c2s[1]) + (c2s[2] + c2s[3])) +
                    ((c2s[4] + c2s[5]) + (c2s[6] + c2s[7])) + c2x;
        out[b] = LN2 * (c2t + __builtin_amdgcn_logf(pt));
      }
    }
    __syncthreads();
  }
}

extern "C" void kernel_launch(void* const* d_in, const int* in_sizes, int n_in,
                              void* d_out, int out_size, void* d_ws, size_t ws_size,
                              hipStream_t stream) {
  const float* feats = (const float*)d_in[0];
  const float* mask  = (const float*)d_in[1];
  const float* trans = (const float*)d_in[2];
  float* out = (float*)d_out;
  hipLaunchKernelGGL(crf_fused, dim3(BATCH), dim3(512), 0, stream,
                     feats, mask, trans, out);
}